// Round 8
// baseline (453.137 us; speedup 1.0000x reference)
//
#include <hip/hip_runtime.h>
#include <hip/hip_bf16.h>
#include <math.h>

#define B_   2
#define N_   2048
#define E_   1024
#define H_   16
#define D_   64
#define E3_  3072
#define M_   (B_ * N_)   // 4096

// log2(e)/8 folded into Q so softmax inner loop is a bare exp2
#define QSCALE 0.18033688011112042f

using short8  = __attribute__((ext_vector_type(8))) short;
using short4v = __attribute__((ext_vector_type(4))) short;
using f32x4   = __attribute__((ext_vector_type(4))) float;
using uint2v  = __attribute__((ext_vector_type(2))) unsigned int;

#define MFMA16(a, b, c)   __builtin_amdgcn_mfma_f32_16x16x32_bf16((a), (b), (c), 0, 0, 0)
#define MFMA16K16(a, b, c) __builtin_amdgcn_mfma_f32_16x16x16bf16_1k((a), (b), (c), 0, 0, 0)

__device__ __forceinline__ unsigned short f2bf(float f) {
    __hip_bfloat16 h = __float2bfloat16(f);
    return __builtin_bit_cast(unsigned short, h);
}

__device__ __forceinline__ float fast_exp2(float x) {
#if __has_builtin(__builtin_amdgcn_exp2f)
    return __builtin_amdgcn_exp2f(x);
#else
    return exp2f(x);
#endif
}

// pack two floats to bf16x2 (round-half-up): 3 VALU ops
__device__ __forceinline__ unsigned int pack_bf16_rh(float lo, float hi) {
    unsigned int ulo = __builtin_bit_cast(unsigned int, lo) + 0x8000u;
    unsigned int uhi = __builtin_bit_cast(unsigned int, hi) + 0x8000u;
#if __has_builtin(__builtin_amdgcn_perm)
    return __builtin_amdgcn_perm(uhi, ulo, 0x07060302u);
#else
    return (uhi & 0xFFFF0000u) | (ulo >> 16);
#endif
}

__device__ __forceinline__ short4v pack4_bf16(float a, float b, float c, float d) {
    uint2v u;
    u.x = pack_bf16_rh(a, b);
    u.y = pack_bf16_rh(c, d);
    return __builtin_bit_cast(short4v, u);
}

// async global->LDS, 16B per lane
__device__ __forceinline__ void gl16(const void* g, void* l) {
    __builtin_amdgcn_global_load_lds(
        (__attribute__((address_space(1))) const void*)g,
        (__attribute__((address_space(3))) void*)l, 16, 0, 0);
}

// ---------------------------------------------------------------------------
// Kernel 0: fp32->bf16: x->xb; w_qkv row-permuted (slot s = c*1024+h*64+d) ->
// wqp; w_proj->wpb.  Block 4096: permuted (+Q-prescaled) bias -> bias_perm.
// ---------------------------------------------------------------------------
__global__ __launch_bounds__(256) void convert_kernel(
    const float* __restrict__ x, const float* __restrict__ wq,
    const float* __restrict__ wp, const float* __restrict__ b_qkv,
    unsigned short* __restrict__ xb, unsigned short* __restrict__ wqp,
    unsigned short* __restrict__ wpb, float* __restrict__ bias_perm)
{
    if (blockIdx.x == 4096) {
        for (int q = threadIdx.x; q < E3_; q += 256) {
            const int c = q >> 10, rem = q & 1023;
            const int h = rem >> 6, d = rem & 63;
            float v = b_qkv[h * 192 + d * 3 + c];
            if (c == 0) v *= QSCALE;
            bias_perm[q] = v;
        }
        return;
    }
    const int o = (blockIdx.x * 256 + threadIdx.x) * 8;
    const float* src;
    unsigned short* dst;
    if (o < 4194304) {                     // x: 4M
        src = x + o; dst = xb + o;
    } else if (o < 7340032) {              // w_qkv permuted: 3M
        const int oo = o - 4194304;
        const int s = oo >> 10, k = oo & 1023;
        const int c = s >> 10, rem = s & 1023;
        const int h = rem >> 6, d = rem & 63;
        src = wq + (size_t)(h * 192 + d * 3 + c) * E_ + k;
        dst = wqp + oo;
    } else {                               // w_proj: 1M
        const int oo = o - 7340032;
        src = wp + oo; dst = wpb + oo;
    }
    float4 a = *(const float4*)src;
    float4 b = *(const float4*)(src + 4);
    uint2v p0, p1;
    p0.x = pack_bf16_rh(a.x, a.y); p0.y = pack_bf16_rh(a.z, a.w);
    p1.x = pack_bf16_rh(b.x, b.y); p1.y = pack_bf16_rh(b.z, b.w);
    *(uint2v*)dst = p0;
    *(uint2v*)(dst + 4) = p1;
}

// ---------------------------------------------------------------------------
// GEMM plumbing: 128x128 tile, BK=32, 4 waves (2x2), global_load_lds(16B),
// XOR-swizzled LDS, ping-pong double buffer (ONE barrier per K-iter).
// ---------------------------------------------------------------------------
#define GEMM_STAGE(dstA, dstB, Aglob, Bglob, k0)                             \
    {                                                                        \
        _Pragma("unroll")                                                    \
        for (int i2 = 0; i2 < 2; ++i2) {                                     \
            const int chunk = wv * 128 + i2 * 64 + lane;                     \
            const int row = chunk >> 2;                                      \
            const int gcg = (chunk & 3) ^ ((row >> 1) & 3);                  \
            const int lbase = (wv * 128 + i2 * 64) * 8;                      \
            gl16(Aglob + (size_t)(bm + row) * E_ + (k0) + gcg * 8,           \
                 &dstA[lbase]);                                              \
            gl16(Bglob + (size_t)(bn + row) * E_ + (k0) + gcg * 8,           \
                 &dstB[lbase]);                                              \
        }                                                                    \
    }

// af[i] = m-dim fragments from MARR; bf[j] = n-dim from NARR
#define GEMM_COMPUTE(MARR, NARR)                                             \
    {                                                                        \
        const int sw = (l15 >> 1) & 3;                                       \
        short8 af[4], bf[4];                                                 \
        _Pragma("unroll")                                                    \
        for (int i = 0; i < 4; ++i) {                                        \
            const int ra = wr * 64 + i * 16 + l15;                           \
            const int rb = wc * 64 + i * 16 + l15;                           \
            af[i] = *(const short8*)&MARR[ra * 32 + ((quad ^ sw) * 8)];      \
            bf[i] = *(const short8*)&NARR[rb * 32 + ((quad ^ sw) * 8)];      \
        }                                                                    \
        _Pragma("unroll")                                                    \
        for (int i = 0; i < 4; ++i)                                          \
            _Pragma("unroll")                                                \
            for (int j = 0; j < 4; ++j)                                      \
                acc[i][j] = MFMA16(af[i], bf[j], acc[i][j]);                 \
    }

#define GEMM_PROLOG                                                          \
    const int t    = threadIdx.x;                                            \
    const int wv   = t >> 6, lane = t & 63;                                  \
    const int quad = lane >> 4, l15 = lane & 15;                             \
    const int wr   = wv & 1, wc = wv >> 1;                                   \
    f32x4 acc[4][4];                                                         \
    _Pragma("unroll")                                                        \
    for (int i = 0; i < 4; ++i)                                              \
        _Pragma("unroll")                                                    \
        for (int j = 0; j < 4; ++j) acc[i][j] = (f32x4){0.f, 0.f, 0.f, 0.f};

// ---------------------------------------------------------------------------
// Kernel 1: merged qkv GEMM over all 3072 output slots (grid 24 x 32).
// ---------------------------------------------------------------------------
__global__ __launch_bounds__(256) void qkv_kernel(
    const unsigned short* __restrict__ A, const unsigned short* __restrict__ Bm,
    const float* __restrict__ bias_perm,
    unsigned short* __restrict__ Q, unsigned short* __restrict__ K,
    unsigned short* __restrict__ VT)
{
    __shared__ __attribute__((aligned(16))) unsigned short As[2][128 * 32];
    __shared__ __attribute__((aligned(16))) unsigned short Bs[2][128 * 32];
    GEMM_PROLOG
    const int bm = blockIdx.y * 128;   // token rows
    const int bn = blockIdx.x * 128;   // s slots
    const int c  = bn >> 10;           // 0=Q,1=K,2=V (uniform per block)

    GEMM_STAGE(As[0], Bs[0], A, Bm, 0);
    if (c < 2) {
        for (int it = 0; it < 32; ++it) {
            const int cur = it & 1;
            __syncthreads();
            if (it < 31)
                GEMM_STAGE(As[cur ^ 1], Bs[cur ^ 1], A, Bm, (it + 1) * 32);
            GEMM_COMPUTE(Bs[cur], As[cur]);   // D[m=s][n=token]
        }
        const float scale = (c == 0) ? QSCALE : 1.0f;
        unsigned short* dst0 = (c == 0) ? Q : K;
#pragma unroll
        for (int i = 0; i < 4; ++i) {
            const int s0 = bn + wr * 64 + i * 16 + quad * 4;
            const int h  = (s0 >> 6) & 15;
            const int d0 = s0 & 63;
            const float4 bq = *(const float4*)(bias_perm + s0);
#pragma unroll
            for (int j = 0; j < 4; ++j) {
                const int row = bm + wc * 64 + j * 16 + l15;
                const int b   = row >> 11, n = row & (N_ - 1);
                const float v0 = fmaf(acc[i][j][0], scale, bq.x);
                const float v1 = fmaf(acc[i][j][1], scale, bq.y);
                const float v2 = fmaf(acc[i][j][2], scale, bq.z);
                const float v3 = fmaf(acc[i][j][3], scale, bq.w);
                uint2v pk;
                pk.x = pack_bf16_rh(v0, v1);
                pk.y = pack_bf16_rh(v2, v3);
                *(uint2v*)(dst0 + (((size_t)b * H_ + h) * N_ + n) * D_ + d0) = pk;
            }
        }
    } else {
        for (int it = 0; it < 32; ++it) {
            const int cur = it & 1;
            __syncthreads();
            if (it < 31)
                GEMM_STAGE(As[cur ^ 1], Bs[cur ^ 1], A, Bm, (it + 1) * 32);
            GEMM_COMPUTE(As[cur], Bs[cur]);   // D[m=token][n=s]
        }
#pragma unroll
        for (int j = 0; j < 4; ++j) {
            const int s = bn + wc * 64 + j * 16 + l15;
            const int h = (s >> 6) & 15, d = s & 63;
            const float bv = bias_perm[s];
#pragma unroll
            for (int i = 0; i < 4; ++i) {
                const int row0 = bm + wr * 64 + i * 16 + quad * 4;
                const int b    = row0 >> 11, n0 = row0 & (N_ - 1);
                uint2v pk;
                pk.x = pack_bf16_rh(acc[i][j][0] + bv, acc[i][j][1] + bv);
                pk.y = pack_bf16_rh(acc[i][j][2] + bv, acc[i][j][3] + bv);
                *(uint2v*)(VT + (((size_t)b * H_ + h) * D_ + d) * N_ + n0) = pk;
            }
        }
    }
}

// ---------------------------------------------------------------------------
// Kernel 2: flash attention, key-partitioned waves.
// Each wave owns 16 keys of the 64-key tile, computes S^T = K_own . Q for all
// 64 q (Q hoisted in regs, 4 B-frag subtiles) -> K LDS reads 2/iter.
// S^T D-layout (q=l15, keys=quad*4+g) == A-layout of mfma 16x16x16 (k=quad*4+j)
// so P feeds PV DIRECTLY FROM REGISTERS (no LDS round-trip).
// V B-frags: 4 b64 reads/iter.  Per-wave partial O over its 16 keys; one-time
// cross-wave reduction through the (dead) tile LDS after the loop.
// LDS: 32 KB tiles (dbuf) + 1 KB lsum = 33 KB.
// ---------------------------------------------------------------------------
__global__ __launch_bounds__(256, 3) void attn_kernel(
    const unsigned short* __restrict__ Q, const unsigned short* __restrict__ K,
    const unsigned short* __restrict__ VT, unsigned short* __restrict__ CTX)
{
    __shared__ __attribute__((aligned(16))) unsigned short pool[16384]; // Ks[2]|Vs[2]
    __shared__ float lsumBuf[4][64];

    const int t    = threadIdx.x;
    const int wv   = t >> 6, lane = t & 63;
    const int quad = lane >> 4, l15 = lane & 15;
    const int qt   = blockIdx.x & 31;   // N/64 q-tiles
    const int bh   = blockIdx.x >> 5;

    const unsigned short* Kp = K + (size_t)bh * N_ * D_;
    const unsigned short* Vp = VT + (size_t)bh * D_ * N_;

    // Q B-frags for 4 q-subtiles (whole block's 64 q rows), hoisted
    short8 qf[4][2];
#pragma unroll
    for (int s = 0; s < 4; ++s) {
        const unsigned short* Qp =
            Q + ((size_t)bh * N_ + qt * 64 + s * 16 + l15) * D_;
        qf[s][0] = *(const short8*)(Qp + quad * 8);
        qf[s][1] = *(const short8*)(Qp + 32 + quad * 8);
    }

    // swizzled offsets (row&7 == l15&7 for all fragment rows)
    const int koff0 = (quad ^ (l15 & 7)) * 8;
    const int koff1 = ((4 + quad) ^ (l15 & 7)) * 8;
    // V b64 frag: key group gg = wv*2 + (quad>>1), sub-offset (quad&1)*4
    const int vslot = (((wv * 2 + (quad >> 1)) ^ (l15 & 7)) * 8) + (quad & 1) * 4;

    f32x4 O[4][4];   // [q-subtile][nt]  partial over this wave's 16 keys
#pragma unroll
    for (int s = 0; s < 4; ++s)
#pragma unroll
        for (int nt = 0; nt < 4; ++nt) O[s][nt] = (f32x4){0.f, 0.f, 0.f, 0.f};
    float lsums[4] = {0.f, 0.f, 0.f, 0.f};

#define ATTN_STAGE(buf, kt)                                                  \
    {                                                                        \
        _Pragma("unroll")                                                    \
        for (int i2 = 0; i2 < 2; ++i2) {                                     \
            const int cch = (wv * 2 + i2) * 64 + lane;                       \
            const int row = cch >> 3, sg = cch & 7;                          \
            const int gc  = (sg ^ (row & 7)) * 8;                            \
            gl16(Kp + (size_t)((kt) * 64 + row) * D_ + gc,                   \
                 &pool[(buf) * 4096 + (wv * 2 + i2) * 512]);                 \
            gl16(Vp + (size_t)row * N_ + (kt) * 64 + gc,                     \
                 &pool[8192 + (buf) * 4096 + (wv * 2 + i2) * 512]);          \
        }                                                                    \
    }

    ATTN_STAGE(0, 0);

    for (int kt = 0; kt < 32; ++kt) {
        const int cur = kt & 1;
        __syncthreads();
        if (kt < 31) ATTN_STAGE(cur ^ 1, kt + 1);

        const unsigned short* Kc = pool + cur * 4096;
        const unsigned short* Vc = pool + 8192 + cur * 4096;

        // A-frags: this wave's 16 key rows only
        const int krow = (wv * 16 + l15) * 64;
        const short8 kf0 = *(const short8*)&Kc[krow + koff0];
        const short8 kf1 = *(const short8*)&Kc[krow + koff1];

        // S^T[key_own][q]: st[s] -> q = s*16+l15, key = wv*16 + quad*4 + g
        f32x4 st[4];
#pragma unroll
        for (int s = 0; s < 4; ++s) st[s] = (f32x4){0.f, 0.f, 0.f, 0.f};
#pragma unroll
        for (int s = 0; s < 4; ++s) st[s] = MFMA16(kf0, qf[s][0], st[s]);
#pragma unroll
        for (int s = 0; s < 4; ++s) st[s] = MFMA16(kf1, qf[s][1], st[s]);

        // softmax numerator + in-register P (A-operand of 16x16x16)
        short4v pa[4];
#pragma unroll
        for (int s = 0; s < 4; ++s) {
            float p0 = fast_exp2(st[s][0]);
            float p1 = fast_exp2(st[s][1]);
            float p2 = fast_exp2(st[s][2]);
            float p3 = fast_exp2(st[s][3]);
            lsums[s] += (p0 + p1) + (p2 + p3);
            pa[s] = pack4_bf16(p0, p1, p2, p3);
        }

        // V B-frags (b64) + PV: O[s][nt] += P[s] . V_own
        short4v bv[4];
#pragma unroll
        for (int nt = 0; nt < 4; ++nt)
            bv[nt] = *(const short4v*)&Vc[(nt * 16 + l15) * 64 + vslot];
#pragma unroll
        for (int s = 0; s < 4; ++s)
#pragma unroll
            for (int nt = 0; nt < 4; ++nt)
                O[s][nt] = MFMA16K16(pa[s], bv[nt], O[s][nt]);
    }
#undef ATTN_STAGE

    // ---- cross-wave reduction ----
    // lsums[s]: partial for q = s*16+l15 over this wave's keys (quad-spread)
#pragma unroll
    for (int s = 0; s < 4; ++s) {
        lsums[s] += __shfl_xor(lsums[s], 16, 64);
        lsums[s] += __shfl_xor(lsums[s], 32, 64);
    }
    if (quad == 0) {
#pragma unroll
        for (int s = 0; s < 4; ++s) lsumBuf[wv][s * 16 + l15] = lsums[s];
    }
    __syncthreads();   // tile reads done (pool reusable) + lsumBuf visible

    float* red = (float*)pool;   // 8192 floats
    const int b = bh >> 4, h = bh & 15;

#pragma unroll
    for (int r = 0; r < 2; ++r) {
        // foreign partial writes for subtiles 2r, 2r+1
#pragma unroll
        for (int so = 0; so < 2; ++so) {
            const int s = 2 * r + so;
            if (wv != s) {
                float* dst = red + so * 4096 + wv * 1024;
#pragma unroll
                for (int nt = 0; nt < 4; ++nt)
#pragma unroll
                    for (int g = 0; g < 4; ++g)
                        dst[(quad * 4 + g) * 64 + nt * 16 + l15] = O[s][nt][g];
            }
        }
        __syncthreads();
        // owners sum + normalize + store
        if ((wv >> 1) == r) {
            const int s = wv;
            const int so = s & 1;
            float ltot[4];
#pragma unroll
            for (int g = 0; g < 4; ++g) {
                float lv = 0.f;
#pragma unroll
                for (int w = 0; w < 4; ++w)
                    lv += lsumBuf[w][s * 16 + quad * 4 + g];
                ltot[g] = 1.0f / lv;
            }
#pragma unroll
            for (int nt = 0; nt < 4; ++nt) {
                f32x4 o = O[s][nt];
#pragma unroll
                for (int w = 0; w < 4; ++w) {
                    if (w == s) continue;
#pragma unroll
                    for (int g = 0; g < 4; ++g)
                        o[g] += red[so * 4096 + w * 1024 +
                                    (quad * 4 + g) * 64 + nt * 16 + l15];
                }
#pragma unroll
                for (int g = 0; g < 4; ++g) {
                    const int qrow = qt * 64 + s * 16 + quad * 4 + g;
                    CTX[((size_t)b * N_ + qrow) * E_ + h * D_ + nt * 16 + l15] =
                        f2bf(o[g] * ltot[g]);
                }
            }
        }
        __syncthreads();   // red reusable for next round
    }
}

// ---------------------------------------------------------------------------
// Kernel 3: out = ctx @ w_proj^T + b_proj.  C^T orientation -> float4 stores.
// ---------------------------------------------------------------------------
__global__ __launch_bounds__(256) void proj_kernel(
    const unsigned short* __restrict__ A, const unsigned short* __restrict__ Bm,
    const float* __restrict__ bias, float* __restrict__ out)
{
    __shared__ __attribute__((aligned(16))) unsigned short As[2][128 * 32];
    __shared__ __attribute__((aligned(16))) unsigned short Bs[2][128 * 32];
    GEMM_PROLOG
    const int bm = blockIdx.y * 128;   // ctx rows
    const int bn = blockIdx.x * 128;   // out cols

    GEMM_STAGE(As[0], Bs[0], A, Bm, 0);
    for (int it = 0; it < 32; ++it) {
        const int cur = it & 1;
        __syncthreads();
        if (it < 31)
            GEMM_STAGE(As[cur ^ 1], Bs[cur ^ 1], A, Bm, (it + 1) * 32);
        GEMM_COMPUTE(Bs[cur], As[cur]);   // D[m=col][n=row]
    }

#pragma unroll
    for (int i = 0; i < 4; ++i) {
        const int col0 = bn + wr * 64 + i * 16 + quad * 4;
        const float4 bp = *(const float4*)(bias + col0);
#pragma unroll
        for (int j = 0; j < 4; ++j) {
            const int row = bm + wc * 64 + j * 16 + l15;
            float4 o;
            o.x = acc[i][j][0] + bp.x;
            o.y = acc[i][j][1] + bp.y;
            o.z = acc[i][j][2] + bp.z;
            o.w = acc[i][j][3] + bp.w;
            *(float4*)(out + (size_t)row * E_ + col0) = o;
        }
    }
}

// ---------------------------------------------------------------------------
extern "C" void kernel_launch(void* const* d_in, const int* in_sizes, int n_in,
                              void* d_out, int out_size, void* d_ws, size_t ws_size,
                              hipStream_t stream)
{
    const float* x      = (const float*)d_in[0];
    const float* w_qkv  = (const float*)d_in[1];
    const float* b_qkv  = (const float*)d_in[2];
    const float* w_proj = (const float*)d_in[3];
    const float* b_proj = (const float*)d_in[4];
    float* out = (float*)d_out;

    // ws (bf16 elems): xb 4M | wqp 3M | wpb 1M | Q 4M | K 4M | VT 4M | CTX 4M
    // then bias_perm (3072 fp32)
    unsigned short* xb  = (unsigned short*)d_ws;
    unsigned short* wqp = xb  + 4194304;
    unsigned short* wpb = wqp + 3145728;
    unsigned short* Q   = wpb + 1048576;
    unsigned short* K   = Q   + 4194304;
    unsigned short* VT  = K   + 4194304;
    unsigned short* CTX = VT  + 4194304;
    float* bias_perm    = (float*)(CTX + 4194304);

    dim3 blk(256);
    convert_kernel<<<dim3(4097), blk, 0, stream>>>(
        x, w_qkv, w_proj, b_qkv, xb, wqp, wpb, bias_perm);

    qkv_kernel<<<dim3(24, 32), blk, 0, stream>>>(xb, wqp, bias_perm, Q, K, VT);

    attn_kernel<<<dim3(B_ * H_ * (N_ / 64)), blk, 0, stream>>>(Q, K, VT, CTX);

    proj_kernel<<<dim3(8, 32), blk, 0, stream>>>(CTX, wpb, b_proj, out);
}

// Round 9
// 199.105 us; speedup vs baseline: 2.2759x; 2.2759x over previous
//
#include <hip/hip_runtime.h>
#include <hip/hip_bf16.h>
#include <math.h>

#define B_   2
#define N_   2048
#define E_   1024
#define H_   16
#define D_   64
#define E3_  3072
#define M_   (B_ * N_)   // 4096

// log2(e)/8 folded into Q so softmax inner loop is a bare exp2
#define QSCALE 0.18033688011112042f

using short8  = __attribute__((ext_vector_type(8))) short;
using short4v = __attribute__((ext_vector_type(4))) short;
using f32x4   = __attribute__((ext_vector_type(4))) float;
using uint2v  = __attribute__((ext_vector_type(2))) unsigned int;

#define MFMA16(a, b, c)    __builtin_amdgcn_mfma_f32_16x16x32_bf16((a), (b), (c), 0, 0, 0)
#define MFMA16K16(a, b, c) __builtin_amdgcn_mfma_f32_16x16x16bf16_1k((a), (b), (c), 0, 0, 0)

__device__ __forceinline__ unsigned short f2bf(float f) {
    __hip_bfloat16 h = __float2bfloat16(f);
    return __builtin_bit_cast(unsigned short, h);
}

__device__ __forceinline__ float fast_exp2(float x) {
#if __has_builtin(__builtin_amdgcn_exp2f)
    return __builtin_amdgcn_exp2f(x);
#else
    return exp2f(x);
#endif
}

// pack two floats to bf16x2 (round-half-up): 3 VALU ops
__device__ __forceinline__ unsigned int pack_bf16_rh(float lo, float hi) {
    unsigned int ulo = __builtin_bit_cast(unsigned int, lo) + 0x8000u;
    unsigned int uhi = __builtin_bit_cast(unsigned int, hi) + 0x8000u;
#if __has_builtin(__builtin_amdgcn_perm)
    return __builtin_amdgcn_perm(uhi, ulo, 0x07060302u);
#else
    return (uhi & 0xFFFF0000u) | (ulo >> 16);
#endif
}

__device__ __forceinline__ short4v pack4_bf16(float a, float b, float c, float d) {
    uint2v u;
    u.x = pack_bf16_rh(a, b);
    u.y = pack_bf16_rh(c, d);
    return __builtin_bit_cast(short4v, u);
}

// async global->LDS, 16B per lane
__device__ __forceinline__ void gl16(const void* g, void* l) {
    __builtin_amdgcn_global_load_lds(
        (__attribute__((address_space(1))) const void*)g,
        (__attribute__((address_space(3))) void*)l, 16, 0, 0);
}

// ---------------------------------------------------------------------------
// Kernel 0: fp32->bf16: x->xb; w_qkv row-permuted (slot s = c*1024+h*64+d) ->
// wqp; w_proj->wpb.  Block 4096: permuted (+Q-prescaled) bias -> bias_perm.
// ---------------------------------------------------------------------------
__global__ __launch_bounds__(256) void convert_kernel(
    const float* __restrict__ x, const float* __restrict__ wq,
    const float* __restrict__ wp, const float* __restrict__ b_qkv,
    unsigned short* __restrict__ xb, unsigned short* __restrict__ wqp,
    unsigned short* __restrict__ wpb, float* __restrict__ bias_perm)
{
    if (blockIdx.x == 4096) {
        for (int q = threadIdx.x; q < E3_; q += 256) {
            const int c = q >> 10, rem = q & 1023;
            const int h = rem >> 6, d = rem & 63;
            float v = b_qkv[h * 192 + d * 3 + c];
            if (c == 0) v *= QSCALE;
            bias_perm[q] = v;
        }
        return;
    }
    const int o = (blockIdx.x * 256 + threadIdx.x) * 8;
    const float* src;
    unsigned short* dst;
    if (o < 4194304) {                     // x: 4M
        src = x + o; dst = xb + o;
    } else if (o < 7340032) {              // w_qkv permuted: 3M
        const int oo = o - 4194304;
        const int s = oo >> 10, k = oo & 1023;
        const int c = s >> 10, rem = s & 1023;
        const int h = rem >> 6, d = rem & 63;
        src = wq + (size_t)(h * 192 + d * 3 + c) * E_ + k;
        dst = wqp + oo;
    } else {                               // w_proj: 1M
        const int oo = o - 7340032;
        src = wp + oo; dst = wpb + oo;
    }
    float4 a = *(const float4*)src;
    float4 b = *(const float4*)(src + 4);
    uint2v p0, p1;
    p0.x = pack_bf16_rh(a.x, a.y); p0.y = pack_bf16_rh(a.z, a.w);
    p1.x = pack_bf16_rh(b.x, b.y); p1.y = pack_bf16_rh(b.z, b.w);
    *(uint2v*)dst = p0;
    *(uint2v*)(dst + 4) = p1;
}

// ---------------------------------------------------------------------------
// GEMM plumbing: 128x128 tile, BK=32, 4 waves (2x2), global_load_lds(16B),
// XOR-swizzled LDS, ping-pong double buffer (ONE barrier per K-iter).
// ---------------------------------------------------------------------------
#define GEMM_STAGE(dstA, dstB, Aglob, Bglob, k0)                             \
    {                                                                        \
        _Pragma("unroll")                                                    \
        for (int i2 = 0; i2 < 2; ++i2) {                                     \
            const int chunk = wv * 128 + i2 * 64 + lane;                     \
            const int row = chunk >> 2;                                      \
            const int gcg = (chunk & 3) ^ ((row >> 1) & 3);                  \
            const int lbase = (wv * 128 + i2 * 64) * 8;                      \
            gl16(Aglob + (size_t)(bm + row) * E_ + (k0) + gcg * 8,           \
                 &dstA[lbase]);                                              \
            gl16(Bglob + (size_t)(bn + row) * E_ + (k0) + gcg * 8,           \
                 &dstB[lbase]);                                              \
        }                                                                    \
    }

// af[i] = m-dim fragments from MARR; bf[j] = n-dim from NARR
#define GEMM_COMPUTE(MARR, NARR)                                             \
    {                                                                        \
        const int sw = (l15 >> 1) & 3;                                       \
        short8 af[4], bf[4];                                                 \
        _Pragma("unroll")                                                    \
        for (int i = 0; i < 4; ++i) {                                        \
            const int ra = wr * 64 + i * 16 + l15;                           \
            const int rb = wc * 64 + i * 16 + l15;                           \
            af[i] = *(const short8*)&MARR[ra * 32 + ((quad ^ sw) * 8)];      \
            bf[i] = *(const short8*)&NARR[rb * 32 + ((quad ^ sw) * 8)];      \
        }                                                                    \
        _Pragma("unroll")                                                    \
        for (int i = 0; i < 4; ++i)                                          \
            _Pragma("unroll")                                                \
            for (int j = 0; j < 4; ++j)                                      \
                acc[i][j] = MFMA16(af[i], bf[j], acc[i][j]);                 \
    }

#define GEMM_PROLOG                                                          \
    const int t    = threadIdx.x;                                            \
    const int wv   = t >> 6, lane = t & 63;                                  \
    const int quad = lane >> 4, l15 = lane & 15;                             \
    const int wr   = wv & 1, wc = wv >> 1;                                   \
    f32x4 acc[4][4];                                                         \
    _Pragma("unroll")                                                        \
    for (int i = 0; i < 4; ++i)                                              \
        _Pragma("unroll")                                                    \
        for (int j = 0; j < 4; ++j) acc[i][j] = (f32x4){0.f, 0.f, 0.f, 0.f};

// ---------------------------------------------------------------------------
// Kernel 1: merged qkv GEMM over all 3072 output slots (grid 24 x 32).
// ---------------------------------------------------------------------------
__global__ __launch_bounds__(256) void qkv_kernel(
    const unsigned short* __restrict__ A, const unsigned short* __restrict__ Bm,
    const float* __restrict__ bias_perm,
    unsigned short* __restrict__ Q, unsigned short* __restrict__ K,
    unsigned short* __restrict__ VT)
{
    __shared__ __attribute__((aligned(16))) unsigned short As[2][128 * 32];
    __shared__ __attribute__((aligned(16))) unsigned short Bs[2][128 * 32];
    GEMM_PROLOG
    const int bm = blockIdx.y * 128;   // token rows
    const int bn = blockIdx.x * 128;   // s slots
    const int c  = bn >> 10;           // 0=Q,1=K,2=V (uniform per block)

    GEMM_STAGE(As[0], Bs[0], A, Bm, 0);
    if (c < 2) {
        for (int it = 0; it < 32; ++it) {
            const int cur = it & 1;
            __syncthreads();
            if (it < 31)
                GEMM_STAGE(As[cur ^ 1], Bs[cur ^ 1], A, Bm, (it + 1) * 32);
            GEMM_COMPUTE(Bs[cur], As[cur]);   // D[m=s][n=token]
        }
        const float scale = (c == 0) ? QSCALE : 1.0f;
        unsigned short* dst0 = (c == 0) ? Q : K;
#pragma unroll
        for (int i = 0; i < 4; ++i) {
            const int s0 = bn + wr * 64 + i * 16 + quad * 4;
            const int h  = (s0 >> 6) & 15;
            const int d0 = s0 & 63;
            const float4 bq = *(const float4*)(bias_perm + s0);
#pragma unroll
            for (int j = 0; j < 4; ++j) {
                const int row = bm + wc * 64 + j * 16 + l15;
                const int b   = row >> 11, n = row & (N_ - 1);
                const float v0 = fmaf(acc[i][j][0], scale, bq.x);
                const float v1 = fmaf(acc[i][j][1], scale, bq.y);
                const float v2 = fmaf(acc[i][j][2], scale, bq.z);
                const float v3 = fmaf(acc[i][j][3], scale, bq.w);
                uint2v pk;
                pk.x = pack_bf16_rh(v0, v1);
                pk.y = pack_bf16_rh(v2, v3);
                *(uint2v*)(dst0 + (((size_t)b * H_ + h) * N_ + n) * D_ + d0) = pk;
            }
        }
    } else {
        for (int it = 0; it < 32; ++it) {
            const int cur = it & 1;
            __syncthreads();
            if (it < 31)
                GEMM_STAGE(As[cur ^ 1], Bs[cur ^ 1], A, Bm, (it + 1) * 32);
            GEMM_COMPUTE(As[cur], Bs[cur]);   // D[m=token][n=s]
        }
#pragma unroll
        for (int j = 0; j < 4; ++j) {
            const int s = bn + wc * 64 + j * 16 + l15;
            const int h = (s >> 6) & 15, d = s & 63;
            const float bv = bias_perm[s];
#pragma unroll
            for (int i = 0; i < 4; ++i) {
                const int row0 = bm + wr * 64 + i * 16 + quad * 4;
                const int b    = row0 >> 11, n0 = row0 & (N_ - 1);
                uint2v pk;
                pk.x = pack_bf16_rh(acc[i][j][0] + bv, acc[i][j][1] + bv);
                pk.y = pack_bf16_rh(acc[i][j][2] + bv, acc[i][j][3] + bv);
                *(uint2v*)(VT + (((size_t)b * H_ + h) * D_ + d) * N_ + n0) = pk;
            }
        }
    }
}

// ---------------------------------------------------------------------------
// Kernel 2: flash attention, 2x2 hybrid partition.
// Wave (wq,wk): q-rows [wq*32, wq*32+32), keys [wk*32, wk*32+32).
// S^T = K_own . Q_own (MFMA 16x16x32); P stays IN REGISTERS as the A-operand
// of mfma 16x16x16 (layout equality verified in r8); V B-frags are b64 reads.
// Per-wave partial O reduced 2-way (across wk) through the dead tile LDS.
// LDS: 32 KB tile pool (dbuf K+V) + 512 B lsum.  VGPR ~125 -> no spill @3/EU.
// ---------------------------------------------------------------------------
__global__ __launch_bounds__(256, 3) void attn_kernel(
    const unsigned short* __restrict__ Q, const unsigned short* __restrict__ K,
    const unsigned short* __restrict__ VT, unsigned short* __restrict__ CTX)
{
    __shared__ __attribute__((aligned(16))) unsigned short pool[16384]; // Ks[2]|Vs[2]
    __shared__ float lsumBuf[2][64];   // [wk][q]

    const int t    = threadIdx.x;
    const int wv   = t >> 6, lane = t & 63;
    const int quad = lane >> 4, l15 = lane & 15;
    const int wq   = wv & 1, wk = wv >> 1;
    const int qt   = blockIdx.x & 31;   // N/64 q-tiles
    const int bh   = blockIdx.x >> 5;

    const unsigned short* Kp = K + (size_t)bh * N_ * D_;
    const unsigned short* Vp = VT + (size_t)bh * D_ * N_;

    // Q B-frags for this wave's 2 q-subtiles (global subtiles wq*2+s)
    short8 qf[2][2];
#pragma unroll
    for (int s = 0; s < 2; ++s) {
        const unsigned short* Qp =
            Q + ((size_t)bh * N_ + qt * 64 + (wq * 2 + s) * 16 + l15) * D_;
        qf[s][0] = *(const short8*)(Qp + quad * 8);
        qf[s][1] = *(const short8*)(Qp + 32 + quad * 8);
    }

    // swizzled K col-group offsets (row&7 == l15&7 for fragment rows)
    const int koff0 = (quad ^ (l15 & 7)) * 8;
    const int koff1 = ((4 + quad) ^ (l15 & 7)) * 8;

    f32x4 O[2][4];   // [q-subtile][nt] partial over this wave's 32 keys
#pragma unroll
    for (int s = 0; s < 2; ++s)
#pragma unroll
        for (int nt = 0; nt < 4; ++nt) O[s][nt] = (f32x4){0.f, 0.f, 0.f, 0.f};
    float lsums[2] = {0.f, 0.f};

#define ATTN_STAGE(buf, kt)                                                  \
    {                                                                        \
        _Pragma("unroll")                                                    \
        for (int i2 = 0; i2 < 2; ++i2) {                                     \
            const int cch = (wv * 2 + i2) * 64 + lane;                       \
            const int row = cch >> 3, sg = cch & 7;                          \
            const int gc  = (sg ^ (row & 7)) * 8;                            \
            gl16(Kp + (size_t)((kt) * 64 + row) * D_ + gc,                   \
                 &pool[(buf) * 4096 + (wv * 2 + i2) * 512]);                 \
            gl16(Vp + (size_t)row * N_ + (kt) * 64 + gc,                     \
                 &pool[8192 + (buf) * 4096 + (wv * 2 + i2) * 512]);          \
        }                                                                    \
    }

    ATTN_STAGE(0, 0);

    for (int kt = 0; kt < 32; ++kt) {
        const int cur = kt & 1;
        __syncthreads();
        if (kt < 31) ATTN_STAGE(cur ^ 1, kt + 1);

        const unsigned short* Kc = pool + cur * 4096;
        const unsigned short* Vc = pool + 8192 + cur * 4096;

        // S^T per key-group kb (16 keys) x q-subtile s
        f32x4 st[2][2];
#pragma unroll
        for (int kb = 0; kb < 2; ++kb) {
            const int krow = (wk * 32 + kb * 16 + l15) * 64;
            const short8 kf0 = *(const short8*)&Kc[krow + koff0];
            const short8 kf1 = *(const short8*)&Kc[krow + koff1];
#pragma unroll
            for (int s = 0; s < 2; ++s) {
                st[kb][s] = (f32x4){0.f, 0.f, 0.f, 0.f};
                st[kb][s] = MFMA16(kf0, qf[s][0], st[kb][s]);
                st[kb][s] = MFMA16(kf1, qf[s][1], st[kb][s]);
            }
        }

        // softmax numerator + in-register P (A-operand of 16x16x16)
        short4v pa[2][2];
#pragma unroll
        for (int kb = 0; kb < 2; ++kb)
#pragma unroll
            for (int s = 0; s < 2; ++s) {
                const float p0 = fast_exp2(st[kb][s][0]);
                const float p1 = fast_exp2(st[kb][s][1]);
                const float p2 = fast_exp2(st[kb][s][2]);
                const float p3 = fast_exp2(st[kb][s][3]);
                lsums[s] += (p0 + p1) + (p2 + p3);
                pa[kb][s] = pack4_bf16(p0, p1, p2, p3);
            }

        // PV: O[s][nt] += P[kb][s] . V(keys of group kb)
#pragma unroll
        for (int kb = 0; kb < 2; ++kb) {
            const int g8 = wk * 4 + kb * 2 + (quad >> 1);
            const int vs = ((g8 ^ (l15 & 7)) * 8) + (quad & 1) * 4;
            short4v bv[4];
#pragma unroll
            for (int nt = 0; nt < 4; ++nt)
                bv[nt] = *(const short4v*)&Vc[(nt * 16 + l15) * 64 + vs];
#pragma unroll
            for (int s = 0; s < 2; ++s)
#pragma unroll
                for (int nt = 0; nt < 4; ++nt)
                    O[s][nt] = MFMA16K16(pa[kb][s], bv[nt], O[s][nt]);
        }
    }
#undef ATTN_STAGE

    // lsums[s] is for q = wq*32 + s*16 + l15, partial over keys (quad-spread)
#pragma unroll
    for (int s = 0; s < 2; ++s) {
        lsums[s] += __shfl_xor(lsums[s], 16, 64);
        lsums[s] += __shfl_xor(lsums[s], 32, 64);
    }
    if (quad == 0) {
#pragma unroll
        for (int s = 0; s < 2; ++s)
            lsumBuf[wk][wq * 32 + s * 16 + l15] = lsums[s];
    }
    __syncthreads();   // tile reads done (pool reusable) + lsumBuf visible

    // O D-layout: q = quad*4+g (row), d = nt*16 + l15 (col)
    float* red = (float*)pool;   // 8192 floats; [wq][qsub 0..31][d 0..63]
    if (wk == 1) {
#pragma unroll
        for (int s = 0; s < 2; ++s)
#pragma unroll
            for (int nt = 0; nt < 4; ++nt)
#pragma unroll
                for (int g = 0; g < 4; ++g)
                    red[wq * 2048 + (s * 16 + quad * 4 + g) * 64 + nt * 16 + l15] =
                        O[s][nt][g];
    }
    __syncthreads();

    if (wk == 0) {
        const int b = bh >> 4, h = bh & 15;
#pragma unroll
        for (int s = 0; s < 2; ++s) {
            float inv[4];
#pragma unroll
            for (int g = 0; g < 4; ++g) {
                const int q = wq * 32 + s * 16 + quad * 4 + g;
                inv[g] = 1.0f / (lsumBuf[0][q] + lsumBuf[1][q]);
            }
#pragma unroll
            for (int nt = 0; nt < 4; ++nt) {
#pragma unroll
                for (int g = 0; g < 4; ++g) {
                    const float o = O[s][nt][g] +
                        red[wq * 2048 + (s * 16 + quad * 4 + g) * 64 + nt * 16 + l15];
                    const int qrow = qt * 64 + wq * 32 + s * 16 + quad * 4 + g;
                    CTX[((size_t)b * N_ + qrow) * E_ + h * D_ + nt * 16 + l15] =
                        f2bf(o * inv[g]);
                }
            }
        }
    }
}

// ---------------------------------------------------------------------------
// Kernel 3: out = ctx @ w_proj^T + b_proj.  128(M) x 64(N) tiles -> 512
// blocks = 2/CU.  C^T orientation -> float4 stores.
// ---------------------------------------------------------------------------
__global__ __launch_bounds__(256) void proj_kernel(
    const unsigned short* __restrict__ A, const unsigned short* __restrict__ Bm,
    const float* __restrict__ bias, float* __restrict__ out)
{
    __shared__ __attribute__((aligned(16))) unsigned short As[2][128 * 32];
    __shared__ __attribute__((aligned(16))) unsigned short Bs[2][64 * 32];
    const int t    = threadIdx.x;
    const int wv   = t >> 6, lane = t & 63;
    const int quad = lane >> 4, l15 = lane & 15;
    const int wr   = wv & 1, wc = wv >> 1;
    const int bm   = blockIdx.y * 128;   // ctx rows
    const int bn   = blockIdx.x * 64;    // out cols

    f32x4 acc[2][4];
#pragma unroll
    for (int i = 0; i < 2; ++i)
#pragma unroll
        for (int j = 0; j < 4; ++j) acc[i][j] = (f32x4){0.f, 0.f, 0.f, 0.f};

#define PROJ_STAGE(dstA, dstB, k0)                                           \
    {                                                                        \
        _Pragma("unroll")                                                    \
        for (int i2 = 0; i2 < 2; ++i2) {                                     \
            const int chunk = wv * 128 + i2 * 64 + lane;                     \
            const int row = chunk >> 2;                                      \
            const int gcg = (chunk & 3) ^ ((row >> 1) & 3);                  \
            gl16(A + (size_t)(bm + row) * E_ + (k0) + gcg * 8,               \
                 &dstA[(wv * 128 + i2 * 64) * 8]);                           \
        }                                                                    \
        {                                                                    \
            const int chunk = wv * 64 + lane;                                \
            const int row = chunk >> 2;                                      \
            const int gcg = (chunk & 3) ^ ((row >> 1) & 3);                  \
            gl16(Bm + (size_t)(bn + row) * E_ + (k0) + gcg * 8,              \
                 &dstB[(wv * 64) * 8]);                                      \
        }                                                                    \
    }

    PROJ_STAGE(As[0], Bs[0], 0);
    for (int it = 0; it < 32; ++it) {
        const int cur = it & 1;
        __syncthreads();
        if (it < 31) PROJ_STAGE(As[cur ^ 1], Bs[cur ^ 1], (it + 1) * 32);
        const int sw = (l15 >> 1) & 3;
        short8 af[2], bf[4];
#pragma unroll
        for (int i = 0; i < 2; ++i)
            af[i] = *(const short8*)&Bs[cur][(wr * 32 + i * 16 + l15) * 32 +
                                             ((quad ^ sw) * 8)];
#pragma unroll
        for (int j = 0; j < 4; ++j)
            bf[j] = *(const short8*)&As[cur][(wc * 64 + j * 16 + l15) * 32 +
                                             ((quad ^ sw) * 8)];
#pragma unroll
        for (int i = 0; i < 2; ++i)
#pragma unroll
            for (int j = 0; j < 4; ++j)
                acc[i][j] = MFMA16(af[i], bf[j], acc[i][j]);   // D[m=col][n=row]
    }
#undef PROJ_STAGE

#pragma unroll
    for (int i = 0; i < 2; ++i) {
        const int col0 = bn + wr * 32 + i * 16 + quad * 4;
        const float4 bp = *(const float4*)(bias + col0);
#pragma unroll
        for (int j = 0; j < 4; ++j) {
            const int row = bm + wc * 64 + j * 16 + l15;
            float4 o;
            o.x = acc[i][j][0] + bp.x;
            o.y = acc[i][j][1] + bp.y;
            o.z = acc[i][j][2] + bp.z;
            o.w = acc[i][j][3] + bp.w;
            *(float4*)(out + (size_t)row * E_ + col0) = o;
        }
    }
}

// ---------------------------------------------------------------------------
extern "C" void kernel_launch(void* const* d_in, const int* in_sizes, int n_in,
                              void* d_out, int out_size, void* d_ws, size_t ws_size,
                              hipStream_t stream)
{
    const float* x      = (const float*)d_in[0];
    const float* w_qkv  = (const float*)d_in[1];
    const float* b_qkv  = (const float*)d_in[2];
    const float* w_proj = (const float*)d_in[3];
    const float* b_proj = (const float*)d_in[4];
    float* out = (float*)d_out;

    // ws (bf16 elems): xb 4M | wqp 3M | wpb 1M | Q 4M | K 4M | VT 4M | CTX 4M
    // then bias_perm (3072 fp32)
    unsigned short* xb  = (unsigned short*)d_ws;
    unsigned short* wqp = xb  + 4194304;
    unsigned short* wpb = wqp + 3145728;
    unsigned short* Q   = wpb + 1048576;
    unsigned short* K   = Q   + 4194304;
    unsigned short* VT  = K   + 4194304;
    unsigned short* CTX = VT  + 4194304;
    float* bias_perm    = (float*)(CTX + 4194304);

    dim3 blk(256);
    convert_kernel<<<dim3(4097), blk, 0, stream>>>(
        x, w_qkv, w_proj, b_qkv, xb, wqp, wpb, bias_perm);

    qkv_kernel<<<dim3(24, 32), blk, 0, stream>>>(xb, wqp, bias_perm, Q, K, VT);

    attn_kernel<<<dim3(B_ * H_ * (N_ / 64)), blk, 0, stream>>>(Q, K, VT, CTX);

    proj_kernel<<<dim3(16, 32), blk, 0, stream>>>(CTX, wpb, b_proj, out);
}

// Round 10
// 198.201 us; speedup vs baseline: 2.2863x; 1.0046x over previous
//
#include <hip/hip_runtime.h>
#include <hip/hip_bf16.h>
#include <math.h>

#define B_   2
#define N_   2048
#define E_   1024
#define H_   16
#define D_   64
#define E3_  3072
#define M_   (B_ * N_)   // 4096

// log2(e)/8 folded into Q so softmax inner loop is a bare exp2
#define QSCALE 0.18033688011112042f

using short8  = __attribute__((ext_vector_type(8))) short;
using short4v = __attribute__((ext_vector_type(4))) short;
using f32x4   = __attribute__((ext_vector_type(4))) float;
using uint2v  = __attribute__((ext_vector_type(2))) unsigned int;

#define MFMA16(a, b, c)    __builtin_amdgcn_mfma_f32_16x16x32_bf16((a), (b), (c), 0, 0, 0)
#define MFMA16K16(a, b, c) __builtin_amdgcn_mfma_f32_16x16x16bf16_1k((a), (b), (c), 0, 0, 0)

__device__ __forceinline__ unsigned short f2bf(float f) {
    __hip_bfloat16 h = __float2bfloat16(f);
    return __builtin_bit_cast(unsigned short, h);
}

__device__ __forceinline__ float fast_exp2(float x) {
#if __has_builtin(__builtin_amdgcn_exp2f)
    return __builtin_amdgcn_exp2f(x);
#else
    return exp2f(x);
#endif
}

// pack two floats to a bf16x2 dword.  gfx950 has v_cvt_pk_bf16_f32 (1 op,
// RNE); fallback = round-half-up bit trick (3 ops).
__device__ __forceinline__ unsigned int pack_bf16_2(float lo, float hi) {
#if __has_builtin(__builtin_amdgcn_cvt_pk_bf16_f32)
    auto pk = __builtin_amdgcn_cvt_pk_bf16_f32(lo, hi);
    return *(const unsigned int*)&pk;
#else
    unsigned int ulo = __builtin_bit_cast(unsigned int, lo) + 0x8000u;
    unsigned int uhi = __builtin_bit_cast(unsigned int, hi) + 0x8000u;
#if __has_builtin(__builtin_amdgcn_perm)
    return __builtin_amdgcn_perm(uhi, ulo, 0x07060302u);
#else
    return (uhi & 0xFFFF0000u) | (ulo >> 16);
#endif
#endif
}

__device__ __forceinline__ short4v pack4_bf16(float a, float b, float c, float d) {
    uint2v u;
    u.x = pack_bf16_2(a, b);
    u.y = pack_bf16_2(c, d);
    return __builtin_bit_cast(short4v, u);
}

// async global->LDS, 16B per lane
__device__ __forceinline__ void gl16(const void* g, void* l) {
    __builtin_amdgcn_global_load_lds(
        (__attribute__((address_space(1))) const void*)g,
        (__attribute__((address_space(3))) void*)l, 16, 0, 0);
}

// ---------------------------------------------------------------------------
// Kernel 0: fp32->bf16: x->xb; w_qkv row-permuted (slot s = c*1024+h*64+d) ->
// wqp; w_proj->wpb.  Block 4096: permuted (+Q-prescaled) bias -> bias_perm.
// ---------------------------------------------------------------------------
__global__ __launch_bounds__(256) void convert_kernel(
    const float* __restrict__ x, const float* __restrict__ wq,
    const float* __restrict__ wp, const float* __restrict__ b_qkv,
    unsigned short* __restrict__ xb, unsigned short* __restrict__ wqp,
    unsigned short* __restrict__ wpb, float* __restrict__ bias_perm)
{
    if (blockIdx.x == 4096) {
        for (int q = threadIdx.x; q < E3_; q += 256) {
            const int c = q >> 10, rem = q & 1023;
            const int h = rem >> 6, d = rem & 63;
            float v = b_qkv[h * 192 + d * 3 + c];
            if (c == 0) v *= QSCALE;
            bias_perm[q] = v;
        }
        return;
    }
    const int o = (blockIdx.x * 256 + threadIdx.x) * 8;
    const float* src;
    unsigned short* dst;
    if (o < 4194304) {                     // x: 4M
        src = x + o; dst = xb + o;
    } else if (o < 7340032) {              // w_qkv permuted: 3M
        const int oo = o - 4194304;
        const int s = oo >> 10, k = oo & 1023;
        const int c = s >> 10, rem = s & 1023;
        const int h = rem >> 6, d = rem & 63;
        src = wq + (size_t)(h * 192 + d * 3 + c) * E_ + k;
        dst = wqp + oo;
    } else {                               // w_proj: 1M
        const int oo = o - 7340032;
        src = wp + oo; dst = wpb + oo;
    }
    float4 a = *(const float4*)src;
    float4 b = *(const float4*)(src + 4);
    uint2v p0, p1;
    p0.x = pack_bf16_2(a.x, a.y); p0.y = pack_bf16_2(a.z, a.w);
    p1.x = pack_bf16_2(b.x, b.y); p1.y = pack_bf16_2(b.z, b.w);
    *(uint2v*)dst = p0;
    *(uint2v*)(dst + 4) = p1;
}

// ---------------------------------------------------------------------------
// GEMM plumbing: 128x128 tile, BK=32, 4 waves (2x2), global_load_lds(16B),
// XOR-swizzled LDS, ping-pong double buffer (ONE barrier per K-iter).
// ---------------------------------------------------------------------------
#define GEMM_STAGE(dstA, dstB, Aglob, Bglob, k0)                             \
    {                                                                        \
        _Pragma("unroll")                                                    \
        for (int i2 = 0; i2 < 2; ++i2) {                                     \
            const int chunk = wv * 128 + i2 * 64 + lane;                     \
            const int row = chunk >> 2;                                      \
            const int gcg = (chunk & 3) ^ ((row >> 1) & 3);                  \
            const int lbase = (wv * 128 + i2 * 64) * 8;                      \
            gl16(Aglob + (size_t)(bm + row) * E_ + (k0) + gcg * 8,           \
                 &dstA[lbase]);                                              \
            gl16(Bglob + (size_t)(bn + row) * E_ + (k0) + gcg * 8,           \
                 &dstB[lbase]);                                              \
        }                                                                    \
    }

// af[i] = m-dim fragments from MARR; bf[j] = n-dim from NARR
#define GEMM_COMPUTE(MARR, NARR)                                             \
    {                                                                        \
        const int sw = (l15 >> 1) & 3;                                       \
        short8 af[4], bf[4];                                                 \
        _Pragma("unroll")                                                    \
        for (int i = 0; i < 4; ++i) {                                        \
            const int ra = wr * 64 + i * 16 + l15;                           \
            const int rb = wc * 64 + i * 16 + l15;                           \
            af[i] = *(const short8*)&MARR[ra * 32 + ((quad ^ sw) * 8)];      \
            bf[i] = *(const short8*)&NARR[rb * 32 + ((quad ^ sw) * 8)];      \
        }                                                                    \
        _Pragma("unroll")                                                    \
        for (int i = 0; i < 4; ++i)                                          \
            _Pragma("unroll")                                                \
            for (int j = 0; j < 4; ++j)                                      \
                acc[i][j] = MFMA16(af[i], bf[j], acc[i][j]);                 \
    }

#define GEMM_PROLOG                                                          \
    const int t    = threadIdx.x;                                            \
    const int wv   = t >> 6, lane = t & 63;                                  \
    const int quad = lane >> 4, l15 = lane & 15;                             \
    const int wr   = wv & 1, wc = wv >> 1;                                   \
    f32x4 acc[4][4];                                                         \
    _Pragma("unroll")                                                        \
    for (int i = 0; i < 4; ++i)                                              \
        _Pragma("unroll")                                                    \
        for (int j = 0; j < 4; ++j) acc[i][j] = (f32x4){0.f, 0.f, 0.f, 0.f};

// ---------------------------------------------------------------------------
// Kernel 1: merged qkv GEMM over all 3072 output slots (grid 24 x 32).
// ---------------------------------------------------------------------------
__global__ __launch_bounds__(256) void qkv_kernel(
    const unsigned short* __restrict__ A, const unsigned short* __restrict__ Bm,
    const float* __restrict__ bias_perm,
    unsigned short* __restrict__ Q, unsigned short* __restrict__ K,
    unsigned short* __restrict__ VT)
{
    __shared__ __attribute__((aligned(16))) unsigned short As[2][128 * 32];
    __shared__ __attribute__((aligned(16))) unsigned short Bs[2][128 * 32];
    GEMM_PROLOG
    const int bm = blockIdx.y * 128;   // token rows
    const int bn = blockIdx.x * 128;   // s slots
    const int c  = bn >> 10;           // 0=Q,1=K,2=V (uniform per block)

    GEMM_STAGE(As[0], Bs[0], A, Bm, 0);
    if (c < 2) {
        for (int it = 0; it < 32; ++it) {
            const int cur = it & 1;
            __syncthreads();
            if (it < 31)
                GEMM_STAGE(As[cur ^ 1], Bs[cur ^ 1], A, Bm, (it + 1) * 32);
            GEMM_COMPUTE(Bs[cur], As[cur]);   // D[m=s][n=token]
        }
        const float scale = (c == 0) ? QSCALE : 1.0f;
        unsigned short* dst0 = (c == 0) ? Q : K;
#pragma unroll
        for (int i = 0; i < 4; ++i) {
            const int s0 = bn + wr * 64 + i * 16 + quad * 4;
            const int h  = (s0 >> 6) & 15;
            const int d0 = s0 & 63;
            const float4 bq = *(const float4*)(bias_perm + s0);
#pragma unroll
            for (int j = 0; j < 4; ++j) {
                const int row = bm + wc * 64 + j * 16 + l15;
                const int b   = row >> 11, n = row & (N_ - 1);
                const float v0 = fmaf(acc[i][j][0], scale, bq.x);
                const float v1 = fmaf(acc[i][j][1], scale, bq.y);
                const float v2 = fmaf(acc[i][j][2], scale, bq.z);
                const float v3 = fmaf(acc[i][j][3], scale, bq.w);
                uint2v pk;
                pk.x = pack_bf16_2(v0, v1);
                pk.y = pack_bf16_2(v2, v3);
                *(uint2v*)(dst0 + (((size_t)b * H_ + h) * N_ + n) * D_ + d0) = pk;
            }
        }
    } else {
        for (int it = 0; it < 32; ++it) {
            const int cur = it & 1;
            __syncthreads();
            if (it < 31)
                GEMM_STAGE(As[cur ^ 1], Bs[cur ^ 1], A, Bm, (it + 1) * 32);
            GEMM_COMPUTE(As[cur], Bs[cur]);   // D[m=token][n=s]
        }
#pragma unroll
        for (int j = 0; j < 4; ++j) {
            const int s = bn + wc * 64 + j * 16 + l15;
            const int h = (s >> 6) & 15, d = s & 63;
            const float bv = bias_perm[s];
#pragma unroll
            for (int i = 0; i < 4; ++i) {
                const int row0 = bm + wr * 64 + i * 16 + quad * 4;
                const int b    = row0 >> 11, n0 = row0 & (N_ - 1);
                uint2v pk;
                pk.x = pack_bf16_2(acc[i][j][0] + bv, acc[i][j][1] + bv);
                pk.y = pack_bf16_2(acc[i][j][2] + bv, acc[i][j][3] + bv);
                *(uint2v*)(VT + (((size_t)b * H_ + h) * D_ + d) * N_ + n0) = pk;
            }
        }
    }
}

// ---------------------------------------------------------------------------
// Kernel 2: flash attention, 2x2 hybrid partition.
// Wave (wq,wk): q-rows [wq*32,+32), keys [wk*32,+32).  S^T = K_own.Q_own;
// P stays in registers as the A-operand of mfma 16x16x16.
// NEW (r10): l = P.1 computed BY MFMA (ones B-operand) -> zero per-iter VALU
// for lsum and no post-loop shuffles; bf16 packs use v_cvt_pk_bf16_f32.
// LDS: 32 KB tile pool (dbuf K+V) + 512 B lsum.
// ---------------------------------------------------------------------------
__global__ __launch_bounds__(256, 3) void attn_kernel(
    const unsigned short* __restrict__ Q, const unsigned short* __restrict__ K,
    const unsigned short* __restrict__ VT, unsigned short* __restrict__ CTX)
{
    __shared__ __attribute__((aligned(16))) unsigned short pool[16384]; // Ks[2]|Vs[2]
    __shared__ float lsumBuf[2][64];   // [wk][q]

    const int t    = threadIdx.x;
    const int wv   = t >> 6, lane = t & 63;
    const int quad = lane >> 4, l15 = lane & 15;
    const int wq   = wv & 1, wk = wv >> 1;
    const int qt   = blockIdx.x & 31;   // N/64 q-tiles
    const int bh   = blockIdx.x >> 5;

    const unsigned short* Kp = K + (size_t)bh * N_ * D_;
    const unsigned short* Vp = VT + (size_t)bh * D_ * N_;

    // Q B-frags for this wave's 2 q-subtiles (global subtiles wq*2+s)
    short8 qf[2][2];
#pragma unroll
    for (int s = 0; s < 2; ++s) {
        const unsigned short* Qp =
            Q + ((size_t)bh * N_ + qt * 64 + (wq * 2 + s) * 16 + l15) * D_;
        qf[s][0] = *(const short8*)(Qp + quad * 8);
        qf[s][1] = *(const short8*)(Qp + 32 + quad * 8);
    }

    // swizzled K col-group offsets (row&7 == l15&7 for fragment rows)
    const int koff0 = (quad ^ (l15 & 7)) * 8;
    const int koff1 = ((4 + quad) ^ (l15 & 7)) * 8;

    // bf16 1.0 x4 for the l = P.1 MFMA
    short4v ones;
    ones[0] = ones[1] = ones[2] = ones[3] = (short)0x3F80;

    f32x4 O[2][4];   // [q-subtile][nt] partial over this wave's 32 keys
#pragma unroll
    for (int s = 0; s < 2; ++s)
#pragma unroll
        for (int nt = 0; nt < 4; ++nt) O[s][nt] = (f32x4){0.f, 0.f, 0.f, 0.f};
    f32x4 Lacc[2] = {{0.f, 0.f, 0.f, 0.f}, {0.f, 0.f, 0.f, 0.f}};

#define ATTN_STAGE(buf, kt)                                                  \
    {                                                                        \
        _Pragma("unroll")                                                    \
        for (int i2 = 0; i2 < 2; ++i2) {                                     \
            const int cch = (wv * 2 + i2) * 64 + lane;                       \
            const int row = cch >> 3, sg = cch & 7;                          \
            const int gc  = (sg ^ (row & 7)) * 8;                            \
            gl16(Kp + (size_t)((kt) * 64 + row) * D_ + gc,                   \
                 &pool[(buf) * 4096 + (wv * 2 + i2) * 512]);                 \
            gl16(Vp + (size_t)row * N_ + (kt) * 64 + gc,                     \
                 &pool[8192 + (buf) * 4096 + (wv * 2 + i2) * 512]);          \
        }                                                                    \
    }

    ATTN_STAGE(0, 0);

    for (int kt = 0; kt < 32; ++kt) {
        const int cur = kt & 1;
        __syncthreads();
        if (kt < 31) ATTN_STAGE(cur ^ 1, kt + 1);

        const unsigned short* Kc = pool + cur * 4096;
        const unsigned short* Vc = pool + 8192 + cur * 4096;

        // S^T per key-group kb (16 keys) x q-subtile s
        f32x4 st[2][2];
#pragma unroll
        for (int kb = 0; kb < 2; ++kb) {
            const int krow = (wk * 32 + kb * 16 + l15) * 64;
            const short8 kf0 = *(const short8*)&Kc[krow + koff0];
            const short8 kf1 = *(const short8*)&Kc[krow + koff1];
#pragma unroll
            for (int s = 0; s < 2; ++s) {
                st[kb][s] = (f32x4){0.f, 0.f, 0.f, 0.f};
                st[kb][s] = MFMA16(kf0, qf[s][0], st[kb][s]);
                st[kb][s] = MFMA16(kf1, qf[s][1], st[kb][s]);
            }
        }

        // softmax numerator: p = exp2(s), packed in-register (A-operand)
        short4v pa[2][2];
#pragma unroll
        for (int kb = 0; kb < 2; ++kb)
#pragma unroll
            for (int s = 0; s < 2; ++s) {
                const float p0 = fast_exp2(st[kb][s][0]);
                const float p1 = fast_exp2(st[kb][s][1]);
                const float p2 = fast_exp2(st[kb][s][2]);
                const float p3 = fast_exp2(st[kb][s][3]);
                pa[kb][s] = pack4_bf16(p0, p1, p2, p3);
            }

        // l partials via MFMA: Lacc[s] += P[kb][s] . 1
#pragma unroll
        for (int kb = 0; kb < 2; ++kb)
#pragma unroll
            for (int s = 0; s < 2; ++s)
                Lacc[s] = MFMA16K16(pa[kb][s], ones, Lacc[s]);

        // PV: O[s][nt] += P[kb][s] . V(keys of group kb)
#pragma unroll
        for (int kb = 0; kb < 2; ++kb) {
            const int g8 = wk * 4 + kb * 2 + (quad >> 1);
            const int vs = ((g8 ^ (l15 & 7)) * 8) + (quad & 1) * 4;
            short4v bv[4];
#pragma unroll
            for (int nt = 0; nt < 4; ++nt)
                bv[nt] = *(const short4v*)&Vc[(nt * 16 + l15) * 64 + vs];
#pragma unroll
            for (int s = 0; s < 2; ++s)
#pragma unroll
                for (int nt = 0; nt < 4; ++nt)
                    O[s][nt] = MFMA16K16(pa[kb][s], bv[nt], O[s][nt]);
        }
    }
#undef ATTN_STAGE

    // Lacc D-layout: row q_local = quad*4+g, all 16 cols identical -> lane
    // l15==0 of each quad publishes its 4 q rows.
    if (l15 == 0) {
#pragma unroll
        for (int s = 0; s < 2; ++s)
#pragma unroll
            for (int g = 0; g < 4; ++g)
                lsumBuf[wk][wq * 32 + s * 16 + quad * 4 + g] = Lacc[s][g];
    }
    __syncthreads();   // tile reads done (pool reusable) + lsumBuf visible

    // O D-layout: q = quad*4+g (row), d = nt*16 + l15 (col)
    float* red = (float*)pool;   // 8192 floats; [wq][qsub 0..31][d 0..63]
    if (wk == 1) {
#pragma unroll
        for (int s = 0; s < 2; ++s)
#pragma unroll
            for (int nt = 0; nt < 4; ++nt)
#pragma unroll
                for (int g = 0; g < 4; ++g)
                    red[wq * 2048 + (s * 16 + quad * 4 + g) * 64 + nt * 16 + l15] =
                        O[s][nt][g];
    }
    __syncthreads();

    if (wk == 0) {
        const int b = bh >> 4, h = bh & 15;
#pragma unroll
        for (int s = 0; s < 2; ++s) {
            float inv[4];
#pragma unroll
            for (int g = 0; g < 4; ++g) {
                const int q = wq * 32 + s * 16 + quad * 4 + g;
                inv[g] = 1.0f / (lsumBuf[0][q] + lsumBuf[1][q]);
            }
#pragma unroll
            for (int nt = 0; nt < 4; ++nt) {
#pragma unroll
                for (int g = 0; g < 4; ++g) {
                    const float o = O[s][nt][g] +
                        red[wq * 2048 + (s * 16 + quad * 4 + g) * 64 + nt * 16 + l15];
                    const int qrow = qt * 64 + wq * 32 + s * 16 + quad * 4 + g;
                    CTX[((size_t)b * N_ + qrow) * E_ + h * D_ + nt * 16 + l15] =
                        f2bf(o * inv[g]);
                }
            }
        }
    }
}

// ---------------------------------------------------------------------------
// Kernel 3: out = ctx @ w_proj^T + b_proj.  128(M) x 64(N) tiles -> 512
// blocks = 2/CU.  C^T orientation -> float4 stores.
// ---------------------------------------------------------------------------
__global__ __launch_bounds__(256) void proj_kernel(
    const unsigned short* __restrict__ A, const unsigned short* __restrict__ Bm,
    const float* __restrict__ bias, float* __restrict__ out)
{
    __shared__ __attribute__((aligned(16))) unsigned short As[2][128 * 32];
    __shared__ __attribute__((aligned(16))) unsigned short Bs[2][64 * 32];
    const int t    = threadIdx.x;
    const int wv   = t >> 6, lane = t & 63;
    const int quad = lane >> 4, l15 = lane & 15;
    const int wr   = wv & 1, wc = wv >> 1;
    const int bm   = blockIdx.y * 128;   // ctx rows
    const int bn   = blockIdx.x * 64;    // out cols

    f32x4 acc[2][4];
#pragma unroll
    for (int i = 0; i < 2; ++i)
#pragma unroll
        for (int j = 0; j < 4; ++j) acc[i][j] = (f32x4){0.f, 0.f, 0.f, 0.f};

#define PROJ_STAGE(dstA, dstB, k0)                                           \
    {                                                                        \
        _Pragma("unroll")                                                    \
        for (int i2 = 0; i2 < 2; ++i2) {                                     \
            const int chunk = wv * 128 + i2 * 64 + lane;                     \
            const int row = chunk >> 2;                                      \
            const int gcg = (chunk & 3) ^ ((row >> 1) & 3);                  \
            gl16(A + (size_t)(bm + row) * E_ + (k0) + gcg * 8,               \
                 &dstA[(wv * 128 + i2 * 64) * 8]);                           \
        }                                                                    \
        {                                                                    \
            const int chunk = wv * 64 + lane;                                \
            const int row = chunk >> 2;                                      \
            const int gcg = (chunk & 3) ^ ((row >> 1) & 3);                  \
            gl16(Bm + (size_t)(bn + row) * E_ + (k0) + gcg * 8,              \
                 &dstB[(wv * 64) * 8]);                                      \
        }                                                                    \
    }

    PROJ_STAGE(As[0], Bs[0], 0);
    for (int it = 0; it < 32; ++it) {
        const int cur = it & 1;
        __syncthreads();
        if (it < 31) PROJ_STAGE(As[cur ^ 1], Bs[cur ^ 1], (it + 1) * 32);
        const int sw = (l15 >> 1) & 3;
        short8 af[2], bf[4];
#pragma unroll
        for (int i = 0; i < 2; ++i)
            af[i] = *(const short8*)&Bs[cur][(wr * 32 + i * 16 + l15) * 32 +
                                             ((quad ^ sw) * 8)];
#pragma unroll
        for (int j = 0; j < 4; ++j)
            bf[j] = *(const short8*)&As[cur][(wc * 64 + j * 16 + l15) * 32 +
                                             ((quad ^ sw) * 8)];
#pragma unroll
        for (int i = 0; i < 2; ++i)
#pragma unroll
            for (int j = 0; j < 4; ++j)
                acc[i][j] = MFMA16(af[i], bf[j], acc[i][j]);   // D[m=col][n=row]
    }
#undef PROJ_STAGE

#pragma unroll
    for (int i = 0; i < 2; ++i) {
        const int col0 = bn + wr * 32 + i * 16 + quad * 4;
        const float4 bp = *(const float4*)(bias + col0);
#pragma unroll
        for (int j = 0; j < 4; ++j) {
            const int row = bm + wc * 64 + j * 16 + l15;
            float4 o;
            o.x = acc[i][j][0] + bp.x;
            o.y = acc[i][j][1] + bp.y;
            o.z = acc[i][j][2] + bp.z;
            o.w = acc[i][j][3] + bp.w;
            *(float4*)(out + (size_t)row * E_ + col0) = o;
        }
    }
}

// ---------------------------------------------------------------------------
extern "C" void kernel_launch(void* const* d_in, const int* in_sizes, int n_in,
                              void* d_out, int out_size, void* d_ws, size_t ws_size,
                              hipStream_t stream)
{
    const float* x      = (const float*)d_in[0];
    const float* w_qkv  = (const float*)d_in[1];
    const float* b_qkv  = (const float*)d_in[2];
    const float* w_proj = (const float*)d_in[3];
    const float* b_proj = (const float*)d_in[4];
    float* out = (float*)d_out;

    // ws (bf16 elems): xb 4M | wqp 3M | wpb 1M | Q 4M | K 4M | VT 4M | CTX 4M
    // then bias_perm (3072 fp32)
    unsigned short* xb  = (unsigned short*)d_ws;
    unsigned short* wqp = xb  + 4194304;
    unsigned short* wpb = wqp + 3145728;
    unsigned short* Q   = wpb + 1048576;
    unsigned short* K   = Q   + 4194304;
    unsigned short* VT  = K   + 4194304;
    unsigned short* CTX = VT  + 4194304;
    float* bias_perm    = (float*)(CTX + 4194304);

    dim3 blk(256);
    convert_kernel<<<dim3(4097), blk, 0, stream>>>(
        x, w_qkv, w_proj, b_qkv, xb, wqp, wpb, bias_perm);

    qkv_kernel<<<dim3(24, 32), blk, 0, stream>>>(xb, wqp, bias_perm, Q, K, VT);

    attn_kernel<<<dim3(B_ * H_ * (N_ / 64)), blk, 0, stream>>>(Q, K, VT, CTX);

    proj_kernel<<<dim3(16, 32), blk, 0, stream>>>(CTX, wpb, b_proj, out);
}